// Round 14
// baseline (7598.431 us; speedup 1.0000x reference)
//
#include <hip/hip_runtime.h>

// Problem constants
#define TT 256
#define DD 128
#define HH 256
#define PP 2048
#define RB 16     // rows per block
#define NBLK 128  // 2048/16
#define NTH 1024  // 16 waves, 4 per SIMD

typedef _Float16 half8 __attribute__((ext_vector_type(8)));
typedef _Float16 half4 __attribute__((ext_vector_type(4)));
typedef float f32x4 __attribute__((ext_vector_type(4)));

#define MFMA16(a, b, c) __builtin_amdgcn_mfma_f32_16x16x32_f16((a), (b), (c), 0, 0, 0)
#define INV2048 (4.8828125e-4f)

__device__ __forceinline__ float fast_sigmoid(float v) {
    return __builtin_amdgcn_rcpf(1.0f + __expf(-v));
}
__device__ __forceinline__ float fast_tanh(float v) {
    const float e2 = __expf(2.0f * v);
    return 1.0f - 2.0f * __builtin_amdgcn_rcpf(e2 + 1.0f);
}

// ---------------------------------------------------------------------------
// Weight fragments (UNCHANGED layout from rounds 6-13 — verified absmax 0):
// sections sec = 2*s+part (s: 0..3 x-k, 4..11 h-k; part 0 hi, 1 lo*2048),
// each section = 48 tiles x 512 halves. Tile tt = chunk*3 + gate covers
// gate-type (tt%3) of units (tt/3)*16..+15; element (m,k): half
// (m + 16*(k>>3))*8 + (k&7).
__global__ void prep_kernel(const float* __restrict__ w_ih, const float* __restrict__ w_hh,
                            const float* __restrict__ protos,
                            _Float16* __restrict__ WF, float* __restrict__ pT) {
    int f = blockIdx.x * blockDim.x + threadIdx.x;
    if (f < 294912) {
        int s = f / 24576, rem = f % 24576;
        int tt = rem / 512, rem2 = rem % 512;
        int m = rem2 >> 5, kl = rem2 & 31;
        int grow = (tt % 3) * 256 + (tt / 3) * 16 + m;
        float v = (s < 4) ? w_ih[grow * DD + s * 32 + kl]
                          : w_hh[grow * HH + (s - 4) * 32 + kl];
        _Float16 hi = (_Float16)v;
        _Float16 lo = (_Float16)((v - (float)hi) * 2048.0f);
        int lane = m + 16 * (kl >> 3);
        int base = ((s * 2 + 0) * 48 + tt) * 512 + lane * 8 + (kl & 7);
        WF[base] = hi;
        WF[base + 48 * 512] = lo;
    }
    if (f < HH * PP) pT[f] = protos[(f & (PP - 1)) * HH + (f >> 11)];
}

// ---------------------------------------------------------------------------
// 16 waves; wave w owns tiles 3w..3w+2; gates fully in-register, 1 barrier/step.
// r12 structure + LDS-ONLY pin of k-step 2 (96 KB, loaded once — zero VGPR
// cost, the r13 lesson). Streamed k-steps {0,1,3..11} keep the wave-staggered
// walk (start w%11, branchless gap-skip over s=2).
__launch_bounds__(NTH)
__global__ void gru_kernel(const float* __restrict__ x,
                           const _Float16* __restrict__ WF,
                           const float* __restrict__ b_ih, const float* __restrict__ b_hh,
                           const float* __restrict__ pT,
                           int* __restrict__ out) {
    // 144 KB pool: frag 48 KB | pin 96 KB (aliased post-loop: hsF 16 KB + red)
    __shared__ __align__(16) unsigned char smem[147456];
    _Float16* const fragB = (_Float16*)smem;                 // [2][24][512]
    _Float16* const pinL  = (_Float16*)(smem + 49152);       // [2 parts][48 tiles][512]
    float* const hsF      = (float*)(smem + 49152);          // post-loop alias
    float (*redv)[RB]     = (float (*)[RB])(smem + 49152 + 16384);
    int   (*redi)[RB]     = (int   (*)[RB])(smem + 49152 + 16384 + 1024);
#define FRAG(b, sec) (fragB + ((b) * 24 + (sec)) * 512)

    const int tid  = threadIdx.x;
    const int lane = tid & 63;
    const int w    = tid >> 6;          // 0..15: chunk id
    const int row0 = blockIdx.x * RB;
    const int lane8 = lane * 8;
    const int t0w   = 3 * w;
    const int sw    = (w >= 11) ? (w - 11) : w;   // stagger start (streamed walk, 11 steps)

    // Biases for this lane's 4 units: j = 16w + (lane>>4)*4 + r
    float bRv[4], bZv[4], bXNv[4], bHNv[4];
    #pragma unroll
    for (int r = 0; r < 4; ++r) {
        const int j = 16 * w + ((lane >> 4) << 2) + r;
        bRv[r]  = b_ih[j] + b_hh[j];
        bZv[r]  = b_ih[HH + j] + b_hh[HH + j];
        bXNv[r] = b_ih[2 * HH + j];
        bHNv[r] = b_hh[2 * HH + j];
    }

    float hprev[4] = {0.f, 0.f, 0.f, 0.f};

    const half8* __restrict__ WH = (const half8*)WF;

    // ---- LDS pin fill: k-step 2 = sections 4,5 (49152 halves = 96 KB) ----
    {
        const half8* src = (const half8*)(WF + 4 * 48 * 512);
        #pragma unroll
        for (int u = 0; u < 6; ++u)
            *(half8*)(pinL + (u * NTH + tid) * 8) = src[u * NTH + tid];
    }

    // x mapping (tid<512): row xn (0..15), 4 consecutive k at xk0
    const int xn = tid >> 5, xk0 = (tid & 31) * 4;
    const float* const xrow = x + (size_t)(row0 + (xn & 15)) * TT * DD + xk0;
    const int xsec = 2 * (xk0 >> 5);
    const int xidx = (((xk0 & 31) >> 3) * 16 + (xn & 15)) * 8 + (xk0 & 7);

    // ---- prime: x_0 fragments + zero h fragments of buf 0 ----
    if (tid < 512) {
        const float4 v = *(const float4*)xrow;
        const float vv[4] = {v.x, v.y, v.z, v.w};
        _Float16 xh[4], xl[4];
        #pragma unroll
        for (int u = 0; u < 4; ++u) {
            xh[u] = (_Float16)vv[u];
            xl[u] = (_Float16)((vv[u] - (float)xh[u]) * 2048.0f);
        }
        *(half4*)(FRAG(0, xsec) + xidx)     = half4{xh[0], xh[1], xh[2], xh[3]};
        *(half4*)(FRAG(0, xsec + 1) + xidx) = half4{xl[0], xl[1], xl[2], xl[3]};
        _Float16* hz = FRAG(0, 8);
        const half8 z8 = {};
        *(half8*)(hz + tid * 16)     = z8;
        *(half8*)(hz + tid * 16 + 8) = z8;
    }
    __syncthreads();   // frag[0] + pinL ready

    for (int t = 0; t < TT; ++t) {
        const int cur = t & 1, nxtb = cur ^ 1;

        float4 pfx = make_float4(0.f, 0.f, 0.f, 0.f);
        const bool havepf = (t + 1 < TT) && (tid < 512);
        if (havepf) pfx = *(const float4*)(xrow + (size_t)(t + 1) * DD);

        // accs: aM/aX = {r, z, n-x-part}; aMh/aXh = n h-part
        f32x4 aM[3], aX[3], aMh, aXh;
        #pragma unroll
        for (int i = 0; i < 3; ++i) { aM[i] = f32x4{0.f,0.f,0.f,0.f}; aX[i] = f32x4{0.f,0.f,0.f,0.f}; }
        aMh = f32x4{0.f,0.f,0.f,0.f}; aXh = f32x4{0.f,0.f,0.f,0.f};

        // ---- streamed k-steps {0,1,3..11}, wave-staggered start ----
        #pragma unroll 2
        for (int i = 0; i < 11; ++i) {
            int m = sw + i; if (m >= 11) m -= 11;
            const int s = m + (m >= 2);          // skip pinned s=2
            const half8 bh = *(const half8*)(FRAG(cur, 2 * s) + lane8);
            const half8 bl = *(const half8*)(FRAG(cur, 2 * s + 1) + lane8);
            const bool isX = (s < 4);
            #pragma unroll
            for (int i2 = 0; i2 < 3; ++i2) {
                const half8 wh = WH[((2 * s) * 48 + t0w + i2) * 64 + lane];
                const half8 wl = WH[((2 * s + 1) * 48 + t0w + i2) * 64 + lane];
                if (i2 == 2 && !isX) {
                    aMh = MFMA16(wh, bh, aMh);
                    aXh = MFMA16(wh, bl, aXh);
                    aXh = MFMA16(wl, bh, aXh);
                } else {
                    aM[i2] = MFMA16(wh, bh, aM[i2]);
                    aX[i2] = MFMA16(wh, bl, aX[i2]);
                    aX[i2] = MFMA16(wl, bh, aX[i2]);
                }
            }
        }

        // ---- pinned k-step 2 (LDS weights, x-type -> aM/aX) ----
        {
            const half8 bh = *(const half8*)(FRAG(cur, 4) + lane8);
            const half8 bl = *(const half8*)(FRAG(cur, 5) + lane8);
            #pragma unroll
            for (int i2 = 0; i2 < 3; ++i2) {
                const half8 wh = *(const half8*)(pinL + ((0 * 48 + t0w + i2) << 9) + lane8);
                const half8 wl = *(const half8*)(pinL + ((1 * 48 + t0w + i2) << 9) + lane8);
                aM[i2] = MFMA16(wh, bh, aM[i2]);
                aX[i2] = MFMA16(wh, bl, aX[i2]);
                aX[i2] = MFMA16(wl, bh, aX[i2]);
            }
        }

        // ---- gates + h update, fully in-register ----
        {
            _Float16 hh_[4], hl_[4];
            #pragma unroll
            for (int r = 0; r < 4; ++r) {
                const float sR  = aM[0][r] + aX[0][r] * INV2048 + bRv[r];
                const float sZ  = aM[1][r] + aX[1][r] * INV2048 + bZv[r];
                const float sXN = aM[2][r] + aX[2][r] * INV2048 + bXNv[r];
                const float sHN = aMh[r]   + aXh[r]   * INV2048 + bHNv[r];
                const float Rg = fast_sigmoid(sR);
                const float Zg = fast_sigmoid(sZ);
                const float Ng = fast_tanh(sXN + Rg * sHN);
                const float h = (1.0f - Zg) * Ng + Zg * hprev[r];
                hprev[r] = h;
                hh_[r] = (_Float16)h;
                hl_[r] = (_Float16)((h - (float)hh_[r]) * 2048.0f);
            }
            const int jb  = 16 * w + ((lane >> 4) << 2);
            const int sec = 2 * (4 + (jb >> 5));
            const int idx = (((jb & 31) >> 3) * 16 + (lane & 15)) * 8 + (jb & 7);
            *(half4*)(FRAG(nxtb, sec) + idx)     = half4{hh_[0], hh_[1], hh_[2], hh_[3]};
            *(half4*)(FRAG(nxtb, sec + 1) + idx) = half4{hl_[0], hl_[1], hl_[2], hl_[3]};
        }

        // ---- x_{t+1} fragments ----
        if (havepf) {
            const float vv[4] = {pfx.x, pfx.y, pfx.z, pfx.w};
            _Float16 xh[4], xl[4];
            #pragma unroll
            for (int u = 0; u < 4; ++u) {
                xh[u] = (_Float16)vv[u];
                xl[u] = (_Float16)((vv[u] - (float)xh[u]) * 2048.0f);
            }
            *(half4*)(FRAG(nxtb, xsec) + xidx)     = half4{xh[0], xh[1], xh[2], xh[3]};
            *(half4*)(FRAG(nxtb, xsec + 1) + xidx) = half4{xl[0], xl[1], xl[2], xl[3]};
        }
        __syncthreads();   // single barrier: frag[nxtb] complete; frag[cur]/pinL reads done
    }

    // ---- final h -> LDS fp32 (pin region now free; aliased) ----
    #pragma unroll
    for (int r = 0; r < 4; ++r) {
        const int j = 16 * w + ((lane >> 4) << 2) + r;
        hsF[j * RB + (lane & 15)] = hprev[r];
    }
    __syncthreads();

    // ---- cdist^2 + argmin: thread covers protos {tid, tid+1024} ----
    float bv[16]; int bi[16];
    #pragma unroll
    for (int r = 0; r < 16; ++r) { bv[r] = 3.4e38f; bi[r] = 0; }
    for (int m = 0; m < 2; ++m) {
        const int p = m * 1024 + tid;
        float d2[16];
        #pragma unroll
        for (int r = 0; r < 16; ++r) d2[r] = 0.f;
        #pragma unroll 2
        for (int k = 0; k < HH; ++k) {
            const float pv = pT[(size_t)k * PP + p];
            #pragma unroll
            for (int g4 = 0; g4 < 4; ++g4) {
                const float4 hv = *(const float4*)&hsF[k * RB + g4 * 4];
                float d;
                d = hv.x - pv; d2[g4 * 4 + 0] += d * d;
                d = hv.y - pv; d2[g4 * 4 + 1] += d * d;
                d = hv.z - pv; d2[g4 * 4 + 2] += d * d;
                d = hv.w - pv; d2[g4 * 4 + 3] += d * d;
            }
        }
        #pragma unroll
        for (int r = 0; r < 16; ++r)
            if (d2[r] < bv[r]) { bv[r] = d2[r]; bi[r] = p; }  // ascending p: lowest on tie
    }
    #pragma unroll
    for (int s = 1; s < 64; s <<= 1) {
        #pragma unroll
        for (int r = 0; r < 16; ++r) {
            const float ov = __shfl_xor(bv[r], s);
            const int   oi = __shfl_xor(bi[r], s);
            if (ov < bv[r] || (ov == bv[r] && oi < bi[r])) { bv[r] = ov; bi[r] = oi; }
        }
    }
    if (lane == 0) {
        #pragma unroll
        for (int r = 0; r < 16; ++r) { redv[w][r] = bv[r]; redi[w][r] = bi[r]; }
    }
    __syncthreads();
    if (tid < RB) {
        float v = redv[0][tid]; int idx = redi[0][tid];
        #pragma unroll
        for (int u = 1; u < 16; ++u) {
            const float ov = redv[u][tid]; const int oi = redi[u][tid];
            if (ov < v || (ov == v && oi < idx)) { v = ov; idx = oi; }
        }
        out[row0 + tid] = idx;
    }
}

extern "C" void kernel_launch(void* const* d_in, const int* in_sizes, int n_in,
                              void* d_out, int out_size, void* d_ws, size_t ws_size,
                              hipStream_t stream) {
    const float* x      = (const float*)d_in[0];
    const float* w_ih   = (const float*)d_in[1];
    const float* w_hh   = (const float*)d_in[2];
    const float* b_ih   = (const float*)d_in[3];
    const float* b_hh   = (const float*)d_in[4];
    const float* protos = (const float*)d_in[5];
    int* out = (int*)d_out;

    _Float16* WF = (_Float16*)d_ws;                                   // 1.125 MB
    float*    pT = (float*)((char*)d_ws + 589824 * sizeof(_Float16)); // 2 MB

    hipLaunchKernelGGL(prep_kernel, dim3((HH * PP + 255) / 256), dim3(256), 0, stream,
                       w_ih, w_hh, protos, WF, pT);
    hipLaunchKernelGGL(gru_kernel, dim3(NBLK), dim3(NTH), 0, stream,
                       x, WF, b_ih, b_hh, pT, out);
}

// Round 15
// 2469.559 us; speedup vs baseline: 3.0768x; 3.0768x over previous
//
#include <hip/hip_runtime.h>

// Problem constants
#define TT 256
#define DD 128
#define HH 256
#define PP 2048
#define RB 16     // rows per block
#define NBLK 128  // 2048/16
#define NTH 1024  // 16 waves, 4 per SIMD

typedef _Float16 half8 __attribute__((ext_vector_type(8)));
typedef _Float16 half4 __attribute__((ext_vector_type(4)));
typedef float f32x4 __attribute__((ext_vector_type(4)));

#define MFMA16(a, b, c) __builtin_amdgcn_mfma_f32_16x16x32_f16((a), (b), (c), 0, 0, 0)
#define INV2048 (4.8828125e-4f)

// Branch-free transcendentals: v_exp_f32 + v_rcp_f32 (~1e-6 abs err; saturate
// correctly for |v| large: exp->inf -> rcp->0 -> tanh->+/-1).
__device__ __forceinline__ float fast_sigmoid(float v) {
    return __builtin_amdgcn_rcpf(1.0f + __expf(-v));
}
__device__ __forceinline__ float fast_tanh(float v) {
    const float e2 = __expf(2.0f * v);
    return 1.0f - 2.0f * __builtin_amdgcn_rcpf(e2 + 1.0f);
}

// ---------------------------------------------------------------------------
// Weight fragments (UNCHANGED layout from rounds 6-14 — verified absmax 0):
// sections sec = 2*s+part (s: 0..3 x-k, 4..11 h-k; part 0 hi, 1 lo*2048),
// each section = 48 tiles x 512 halves. Tile tt = chunk*3 + gate covers
// gate-type (tt%3) of units (tt/3)*16..+15; element (m,k): half
// (m + 16*(k>>3))*8 + (k&7).
__global__ void prep_kernel(const float* __restrict__ w_ih, const float* __restrict__ w_hh,
                            const float* __restrict__ protos,
                            _Float16* __restrict__ WF, float* __restrict__ pT) {
    int f = blockIdx.x * blockDim.x + threadIdx.x;
    if (f < 294912) {
        int s = f / 24576, rem = f % 24576;
        int tt = rem / 512, rem2 = rem % 512;
        int m = rem2 >> 5, kl = rem2 & 31;
        int grow = (tt % 3) * 256 + (tt / 3) * 16 + m;
        float v = (s < 4) ? w_ih[grow * DD + s * 32 + kl]
                          : w_hh[grow * HH + (s - 4) * 32 + kl];
        _Float16 hi = (_Float16)v;
        _Float16 lo = (_Float16)((v - (float)hi) * 2048.0f);
        int lane = m + 16 * (kl >> 3);
        int base = ((s * 2 + 0) * 48 + tt) * 512 + lane * 8 + (kl & 7);
        WF[base] = hi;
        WF[base + 48 * 512] = lo;
    }
    if (f < HH * PP) pT[f] = protos[(f & (PP - 1)) * HH + (f >> 11)];
}

// ---------------------------------------------------------------------------
// 16 waves; wave w owns tiles 3w..3w+2 = chunk w x gates {r,z,n}; gates fully
// in-register, 1 barrier/step. Wave-staggered k-step order: wave w starts its
// 12-section walk at section w%12 (de-correlates load bursts & stall windows).
// LDS kept at 67.5 KB: two blocks co-reside per CU and share the weight
// stream through L1/L2 (r10/r12 vs r11/r13/r14 evidence — do NOT break this).
__launch_bounds__(NTH)
__global__ void gru_kernel(const float* __restrict__ x,
                           const _Float16* __restrict__ WF,
                           const float* __restrict__ b_ih, const float* __restrict__ b_hh,
                           const float* __restrict__ pT,
                           int* __restrict__ out) {
    __shared__ __align__(16) _Float16 fragB[2 * 24 * 512];  // 48 KB activation fragments
    __shared__ float hsF[HH * RB];                          // 16 KB final h
    __shared__ float redv[16][RB];
    __shared__ int   redi[16][RB];
#define FRAG(b, sec) (fragB + ((b) * 24 + (sec)) * 512)

    const int tid  = threadIdx.x;
    const int lane = tid & 63;
    const int w    = tid >> 6;          // 0..15: chunk id
    const int row0 = blockIdx.x * RB;
    const int lane8 = lane * 8;
    const int t0w   = 3 * w;
    const int sw    = (w >= 12) ? (w - 12) : w;   // k-step rotation start

    // Biases for this lane's 4 units: j = 16w + (lane>>4)*4 + r
    float bRv[4], bZv[4], bXNv[4], bHNv[4];
    #pragma unroll
    for (int r = 0; r < 4; ++r) {
        const int j = 16 * w + ((lane >> 4) << 2) + r;
        bRv[r]  = b_ih[j] + b_hh[j];
        bZv[r]  = b_ih[HH + j] + b_hh[HH + j];
        bXNv[r] = b_ih[2 * HH + j];
        bHNv[r] = b_hh[2 * HH + j];
    }

    float hprev[4] = {0.f, 0.f, 0.f, 0.f};

    // x mapping (tid<512): row xn (0..15), 4 consecutive k at xk0
    const int xn = tid >> 5, xk0 = (tid & 31) * 4;
    const float* const xrow = x + (size_t)(row0 + (xn & 15)) * TT * DD + xk0;
    const int xsec = 2 * (xk0 >> 5);
    const int xidx = (((xk0 & 31) >> 3) * 16 + (xn & 15)) * 8 + (xk0 & 7);

    // ---- prime: x_0 fragments + zero h fragments of buf 0 ----
    if (tid < 512) {
        const float4 v = *(const float4*)xrow;
        const float vv[4] = {v.x, v.y, v.z, v.w};
        _Float16 xh[4], xl[4];
        #pragma unroll
        for (int u = 0; u < 4; ++u) {
            xh[u] = (_Float16)vv[u];
            xl[u] = (_Float16)((vv[u] - (float)xh[u]) * 2048.0f);
        }
        *(half4*)(FRAG(0, xsec) + xidx)     = half4{xh[0], xh[1], xh[2], xh[3]};
        *(half4*)(FRAG(0, xsec + 1) + xidx) = half4{xl[0], xl[1], xl[2], xl[3]};
        _Float16* hz = FRAG(0, 8);
        const half8 z8 = {};
        *(half8*)(hz + tid * 16)     = z8;
        *(half8*)(hz + tid * 16 + 8) = z8;
    }
    __syncthreads();

    const half8* __restrict__ WH = (const half8*)WF;

    for (int t = 0; t < TT; ++t) {
        const int cur = t & 1, nxtb = cur ^ 1;

        float4 pfx = make_float4(0.f, 0.f, 0.f, 0.f);
        const bool havepf = (t + 1 < TT) && (tid < 512);
        if (havepf) pfx = *(const float4*)(xrow + (size_t)(t + 1) * DD);

        // accs: aM/aX = {r, z, n-x-part}; aMh/aXh = n h-part
        f32x4 aM[3], aX[3], aMh, aXh;
        #pragma unroll
        for (int i = 0; i < 3; ++i) { aM[i] = f32x4{0.f,0.f,0.f,0.f}; aX[i] = f32x4{0.f,0.f,0.f,0.f}; }
        aMh = f32x4{0.f,0.f,0.f,0.f}; aXh = f32x4{0.f,0.f,0.f,0.f};

        // ---- 12 k-steps, wave-staggered start (s covers 0..11 exactly once).
        // s<4: x k-steps (all 3 tiles -> aM/aX); s>=4: h k-steps (n -> aMh/aXh).
        #pragma unroll 2
        for (int i = 0; i < 12; ++i) {
            int s = sw + i; if (s >= 12) s -= 12;
            const half8 bh = *(const half8*)(FRAG(cur, 2 * s) + lane8);
            const half8 bl = *(const half8*)(FRAG(cur, 2 * s + 1) + lane8);
            const bool isX = (s < 4);
            #pragma unroll
            for (int i2 = 0; i2 < 3; ++i2) {
                const half8 wh = WH[((2 * s) * 48 + t0w + i2) * 64 + lane];
                const half8 wl = WH[((2 * s + 1) * 48 + t0w + i2) * 64 + lane];
                if (i2 == 2 && !isX) {
                    aMh = MFMA16(wh, bh, aMh);
                    aXh = MFMA16(wh, bl, aXh);
                    aXh = MFMA16(wl, bh, aXh);
                } else {
                    aM[i2] = MFMA16(wh, bh, aM[i2]);
                    aX[i2] = MFMA16(wh, bl, aX[i2]);
                    aX[i2] = MFMA16(wl, bh, aX[i2]);
                }
            }
        }

        // ---- gates + h update, fully in-register ----
        {
            _Float16 hh_[4], hl_[4];
            #pragma unroll
            for (int r = 0; r < 4; ++r) {
                const float sR  = aM[0][r] + aX[0][r] * INV2048 + bRv[r];
                const float sZ  = aM[1][r] + aX[1][r] * INV2048 + bZv[r];
                const float sXN = aM[2][r] + aX[2][r] * INV2048 + bXNv[r];
                const float sHN = aMh[r]   + aXh[r]   * INV2048 + bHNv[r];
                const float Rg = fast_sigmoid(sR);
                const float Zg = fast_sigmoid(sZ);
                const float Ng = fast_tanh(sXN + Rg * sHN);
                const float h = (1.0f - Zg) * Ng + Zg * hprev[r];
                hprev[r] = h;
                hh_[r] = (_Float16)h;
                hl_[r] = (_Float16)((h - (float)hh_[r]) * 2048.0f);
            }
            const int jb  = 16 * w + ((lane >> 4) << 2);
            const int sec = 2 * (4 + (jb >> 5));
            const int idx = (((jb & 31) >> 3) * 16 + (lane & 15)) * 8 + (jb & 7);
            *(half4*)(FRAG(nxtb, sec) + idx)     = half4{hh_[0], hh_[1], hh_[2], hh_[3]};
            *(half4*)(FRAG(nxtb, sec + 1) + idx) = half4{hl_[0], hl_[1], hl_[2], hl_[3]};
        }

        // ---- x_{t+1} fragments ----
        if (havepf) {
            const float vv[4] = {pfx.x, pfx.y, pfx.z, pfx.w};
            _Float16 xh[4], xl[4];
            #pragma unroll
            for (int u = 0; u < 4; ++u) {
                xh[u] = (_Float16)vv[u];
                xl[u] = (_Float16)((vv[u] - (float)xh[u]) * 2048.0f);
            }
            *(half4*)(FRAG(nxtb, xsec) + xidx)     = half4{xh[0], xh[1], xh[2], xh[3]};
            *(half4*)(FRAG(nxtb, xsec + 1) + xidx) = half4{xl[0], xl[1], xl[2], xl[3]};
        }
        __syncthreads();   // single barrier: frag[nxtb] complete; frag[cur] reads done
    }

    // ---- final h -> LDS fp32 ----
    #pragma unroll
    for (int r = 0; r < 4; ++r) {
        const int j = 16 * w + ((lane >> 4) << 2) + r;
        hsF[j * RB + (lane & 15)] = hprev[r];
    }
    __syncthreads();

    // ---- cdist^2 + argmin: thread covers protos {tid, tid+1024} ----
    float bv[16]; int bi[16];
    #pragma unroll
    for (int r = 0; r < 16; ++r) { bv[r] = 3.4e38f; bi[r] = 0; }
    for (int m = 0; m < 2; ++m) {
        const int p = m * 1024 + tid;
        float d2[16];
        #pragma unroll
        for (int r = 0; r < 16; ++r) d2[r] = 0.f;
        #pragma unroll 2
        for (int k = 0; k < HH; ++k) {
            const float pv = pT[(size_t)k * PP + p];
            #pragma unroll
            for (int g4 = 0; g4 < 4; ++g4) {
                const float4 hv = *(const float4*)&hsF[k * RB + g4 * 4];
                float d;
                d = hv.x - pv; d2[g4 * 4 + 0] += d * d;
                d = hv.y - pv; d2[g4 * 4 + 1] += d * d;
                d = hv.z - pv; d2[g4 * 4 + 2] += d * d;
                d = hv.w - pv; d2[g4 * 4 + 3] += d * d;
            }
        }
        #pragma unroll
        for (int r = 0; r < 16; ++r)
            if (d2[r] < bv[r]) { bv[r] = d2[r]; bi[r] = p; }  // ascending p: lowest on tie
    }
    #pragma unroll
    for (int s = 1; s < 64; s <<= 1) {
        #pragma unroll
        for (int r = 0; r < 16; ++r) {
            const float ov = __shfl_xor(bv[r], s);
            const int   oi = __shfl_xor(bi[r], s);
            if (ov < bv[r] || (ov == bv[r] && oi < bi[r])) { bv[r] = ov; bi[r] = oi; }
        }
    }
    if (lane == 0) {
        #pragma unroll
        for (int r = 0; r < 16; ++r) { redv[w][r] = bv[r]; redi[w][r] = bi[r]; }
    }
    __syncthreads();
    if (tid < RB) {
        float v = redv[0][tid]; int idx = redi[0][tid];
        #pragma unroll
        for (int u = 1; u < 16; ++u) {
            const float ov = redv[u][tid]; const int oi = redi[u][tid];
            if (ov < v || (ov == v && oi < idx)) { v = ov; idx = oi; }
        }
        out[row0 + tid] = idx;
    }
}

extern "C" void kernel_launch(void* const* d_in, const int* in_sizes, int n_in,
                              void* d_out, int out_size, void* d_ws, size_t ws_size,
                              hipStream_t stream) {
    const float* x      = (const float*)d_in[0];
    const float* w_ih   = (const float*)d_in[1];
    const float* w_hh   = (const float*)d_in[2];
    const float* b_ih   = (const float*)d_in[3];
    const float* b_hh   = (const float*)d_in[4];
    const float* protos = (const float*)d_in[5];
    int* out = (int*)d_out;

    _Float16* WF = (_Float16*)d_ws;                                   // 1.125 MB
    float*    pT = (float*)((char*)d_ws + 589824 * sizeof(_Float16)); // 2 MB

    hipLaunchKernelGGL(prep_kernel, dim3((HH * PP + 255) / 256), dim3(256), 0, stream,
                       w_ih, w_hh, protos, WF, pT);
    hipLaunchKernelGGL(gru_kernel, dim3(NBLK), dim3(NTH), 0, stream,
                       x, WF, b_ih, b_hh, pT, out);
}